// Round 1
// baseline (309.900 us; speedup 1.0000x reference)
//
#include <hip/hip_runtime.h>
#include <math.h>

// Problem sizes (fixed by the reference)
#define B   4
#define TQ  256
#define TV  1024
#define D   512
#define A   128

#define LOG2E     1.4426950408889634f
#define TWO_LOG2E 2.8853900817779268f
#define NEG_BIG_F (-1e9f)

// ---------------------------------------------------------------------------
// Projection + exp(2x): E[r,a] = exp(2 * (X[r,:] @ W[:,a] + bias[a]))
// One block = 8 rows, 128 threads (one per output column a).
// W reads are wave-coalesced (lane a -> W[d*A + a]); rows staged in LDS so
// each W element is reused across 8 rows (8 FMA per global load).
// ---------------------------------------------------------------------------
__global__ __launch_bounds__(128) void proj_exp_kernel(
    const float* __restrict__ X, const float* __restrict__ W,
    const float* __restrict__ bias, float* __restrict__ E) {
  const int ROWS = 8;
  __shared__ float xs[ROWS][D];
  int r0 = blockIdx.x * ROWS;
  for (int i = threadIdx.x; i < ROWS * D; i += 128) {
    xs[i >> 9][i & (D - 1)] = X[(size_t)r0 * D + i];
  }
  __syncthreads();
  int a = threadIdx.x;
  float bz = bias[a];
  float acc[ROWS];
#pragma unroll
  for (int j = 0; j < ROWS; ++j) acc[j] = bz;
#pragma unroll 4
  for (int d = 0; d < D; ++d) {
    float w = W[d * A + a];
#pragma unroll
    for (int j = 0; j < ROWS; ++j) acc[j] = fmaf(xs[j][d], w, acc[j]);
  }
#pragma unroll
  for (int j = 0; j < ROWS; ++j)
    E[(size_t)(r0 + j) * A + a] = __builtin_amdgcn_exp2f(acc[j] * TWO_LOG2E);
}

// ---------------------------------------------------------------------------
// Scores + softmax for one (b,q) row.
// score[v] = sum_a v_a * tanh(q_a + k_va)
//          = sumV - 2 * sum_a v_a / (Eq[a]*Ek[v,a] + 1)
// Then masked softmax over v; writes attn row (fp32) to workspace.
// Block = 256 threads, each handles 4 v's.
// ---------------------------------------------------------------------------
__global__ __launch_bounds__(256) void score_softmax_kernel(
    const float* __restrict__ Eq, const float* __restrict__ Ek,
    const float* __restrict__ attn_v, const int* __restrict__ mask,
    float* __restrict__ attn) {
  __shared__ float eqs[A];
  __shared__ float avs[A];
  __shared__ float sc[TV];
  __shared__ float red[8];

  int bq = blockIdx.x;      // b*TQ + q
  int b  = bq >> 8;         // TQ == 256
  int tid = threadIdx.x;

  if (tid < A) {
    eqs[tid] = Eq[(size_t)bq * A + tid];
    avs[tid] = attn_v[tid];
  }
  __syncthreads();

  float sumV = 0.f;
#pragma unroll 8
  for (int i = 0; i < A; ++i) sumV += avs[i];

  const int vpt = TV / 256;  // 4
  float lmax = -INFINITY;
#pragma unroll
  for (int u = 0; u < vpt; ++u) {
    int v = tid + u * 256;
    const float4* ek = (const float4*)(Ek + ((size_t)b * TV + v) * A);
    const float4* g4 = (const float4*)eqs;
    const float4* a4 = (const float4*)avs;
    float s2 = 0.f;
#pragma unroll 8
    for (int i = 0; i < A / 4; ++i) {
      float4 e  = ek[i];
      float4 g  = g4[i];
      float4 av = a4[i];
      s2 += av.x * __builtin_amdgcn_rcpf(fmaf(e.x, g.x, 1.f));
      s2 += av.y * __builtin_amdgcn_rcpf(fmaf(e.y, g.y, 1.f));
      s2 += av.z * __builtin_amdgcn_rcpf(fmaf(e.z, g.z, 1.f));
      s2 += av.w * __builtin_amdgcn_rcpf(fmaf(e.w, g.w, 1.f));
    }
    float s = sumV - 2.f * s2;
    s += (1.f - (float)mask[b * TV + v]) * NEG_BIG_F;
    sc[v] = s;
    lmax = fmaxf(lmax, s);
  }

  // block max
  for (int off = 32; off > 0; off >>= 1)
    lmax = fmaxf(lmax, __shfl_down(lmax, off, 64));
  if ((tid & 63) == 0) red[tid >> 6] = lmax;
  __syncthreads();
  if (tid == 0)
    red[4] = fmaxf(fmaxf(red[0], red[1]), fmaxf(red[2], red[3]));
  __syncthreads();
  float m = red[4];

  float lsum = 0.f;
#pragma unroll
  for (int u = 0; u < vpt; ++u) {
    int v = tid + u * 256;
    float e = __builtin_amdgcn_exp2f((sc[v] - m) * LOG2E);
    sc[v] = e;
    lsum += e;
  }
  for (int off = 32; off > 0; off >>= 1)
    lsum += __shfl_down(lsum, off, 64);
  __syncthreads();   // everyone done reading red[4]
  if ((tid & 63) == 0) red[tid >> 6] = lsum;
  __syncthreads();
  if (tid == 0) red[4] = (red[0] + red[1]) + (red[2] + red[3]);
  __syncthreads();
  float inv = 1.f / red[4];

  float* arow = attn + (size_t)bq * TV;
#pragma unroll
  for (int u = 0; u < vpt; ++u) {
    int v = tid + u * 256;
    arow[v] = sc[v] * inv;
  }
}

// ---------------------------------------------------------------------------
// out[b,q,:] = sum_v attn[b,q,v] * inputs[b,v,:]
// Tile: 16 q x 128 d per block; attn chunk staged in LDS (broadcast reads);
// inputs loads coalesced float2 over d. 16x q-reuse of inputs traffic.
// grid = (dt=4, qt=16, b=4), block = 256.
// ---------------------------------------------------------------------------
__global__ __launch_bounds__(256) void pv_kernel(
    const float* __restrict__ attn, const float* __restrict__ X,
    float* __restrict__ out) {
  const int QT = 16, DT = 128, VC = 128;
  __shared__ float at[QT][VC];
  int b = blockIdx.z, qt = blockIdx.y, dt = blockIdx.x;
  int tid  = threadIdx.x;
  int dcol = tid & 63;   // 64 float2 columns = 128 d
  int qg   = tid >> 6;   // 0..3, 4 q's each
  int d0 = dt * DT + dcol * 2;
  int q0 = qt * QT;

  float2 acc[4];
#pragma unroll
  for (int j = 0; j < 4; ++j) acc[j] = make_float2(0.f, 0.f);

  for (int vc = 0; vc < TV; vc += VC) {
    for (int i = tid; i < QT * VC; i += 256) {
      at[i >> 7][i & (VC - 1)] =
          attn[(size_t)(b * TQ + q0 + (i >> 7)) * TV + vc + (i & (VC - 1))];
    }
    __syncthreads();
#pragma unroll 4
    for (int vi = 0; vi < VC; ++vi) {
      float2 x = *(const float2*)(X + (size_t)(b * TV + vc + vi) * D + d0);
#pragma unroll
      for (int j = 0; j < 4; ++j) {
        float w = at[qg * 4 + j][vi];
        acc[j].x = fmaf(w, x.x, acc[j].x);
        acc[j].y = fmaf(w, x.y, acc[j].y);
      }
    }
    __syncthreads();
  }
#pragma unroll
  for (int j = 0; j < 4; ++j) {
    int q = q0 + qg * 4 + j;
    *(float2*)(out + (size_t)(b * TQ + q) * D + d0) = acc[j];
  }
}

extern "C" void kernel_launch(void* const* d_in, const int* in_sizes, int n_in,
                              void* d_out, int out_size, void* d_ws, size_t ws_size,
                              hipStream_t stream) {
  const float* inputs  = (const float*)d_in[0];  // [B,TV,D]
  const float* context = (const float*)d_in[1];  // [B,TQ,D]
  const int*   mask    = (const int*)d_in[2];    // [B,TV]
  const float* Wk      = (const float*)d_in[3];  // [D,A]
  const float* bk      = (const float*)d_in[4];  // [A]
  const float* Wq      = (const float*)d_in[5];  // [D,A]
  const float* bq      = (const float*)d_in[6];  // [A]
  const float* attn_v  = (const float*)d_in[7];  // [A]
  float* out = (float*)d_out;                    // [B,TQ,D]

  // Workspace layout (fp32): Eq | Ek | attn  = 0.5MB + 2MB + 4MB
  float* Eq   = (float*)d_ws;           // B*TQ*A
  float* Ek   = Eq + B * TQ * A;        // B*TV*A
  float* attn = Ek + B * TV * A;        // B*TQ*TV

  proj_exp_kernel<<<B * TQ / 8, 128, 0, stream>>>(context, Wq, bq, Eq);
  proj_exp_kernel<<<B * TV / 8, 128, 0, stream>>>(inputs, Wk, bk, Ek);
  score_softmax_kernel<<<B * TQ, 256, 0, stream>>>(Eq, Ek, attn_v, mask, attn);
  pv_kernel<<<dim3(4, 16, 4), 256, 0, stream>>>(attn, inputs, out);
}

// Round 2
// 206.904 us; speedup vs baseline: 1.4978x; 1.4978x over previous
//
#include <hip/hip_runtime.h>
#include <math.h>

// Problem sizes (fixed by the reference)
#define B   4
#define TQ  256
#define TV  1024
#define D   512
#define A   128

#define LOG2E     1.4426950408889634f
#define TWO_LOG2E 2.8853900817779268f
#define NEG_BIG_F (-1e9f)

#define QBLK (B * TQ / 8)   // 128 q-projection blocks
#define KBLK (B * TV / 8)   // 512 k-projection blocks

// ---------------------------------------------------------------------------
// Fused projection + exp(2x) for BOTH q and k.
//   q path: Eq[r, a]            = exp(2*(ctx[r,:]@Wq[:,a] + bq[a]))   [row-major]
//   k path: EkT[b, a, v]        = exp(2*(inp[r,:]@Wk[:,a] + bk[a]))   [TRANSPOSED]
// Block: 256 threads = (a 0..127, half h 0..1 splitting d). 8 rows/block.
// X rows staged in LDS (float4 reads); halves reduced through LDS; k output
// transposed through LDS so global stores are 32B-segment coalesced.
// ---------------------------------------------------------------------------
__global__ __launch_bounds__(256) void proj_exp_kernel(
    const float* __restrict__ ctx, const float* __restrict__ inp,
    const float* __restrict__ Wq, const float* __restrict__ bq,
    const float* __restrict__ Wk, const float* __restrict__ bk,
    float* __restrict__ Eq, float* __restrict__ EkT) {
  __shared__ float xs[8][D];        // 16 KB
  __shared__ float ps[8][2][A];     // 8 KB   (row j, half, a)
  __shared__ float es[A][9];        // 4.6 KB (transpose staging, +1 pad)

  bool isQ = blockIdx.x < QBLK;
  const float* X; const float* W; const float* bias; int r0;
  if (isQ) { X = ctx; W = Wq; bias = bq; r0 = blockIdx.x * 8; }
  else     { X = inp; W = Wk; bias = bk; r0 = (blockIdx.x - QBLK) * 8; }

  // stage 8 rows of X (float4, coalesced)
  {
    const float4* Xv = (const float4*)(X + (size_t)r0 * D);
    float4* xsv = (float4*)&xs[0][0];
    for (int i = threadIdx.x; i < 8 * D / 4; i += 256) xsv[i] = Xv[i];
  }
  __syncthreads();

  int a = threadIdx.x & 127;
  int h = threadIdx.x >> 7;        // 0..1, splits d-range
  float acc[8];
#pragma unroll
  for (int j = 0; j < 8; ++j) acc[j] = 0.f;

  int dbase = h * (D / 2);
#pragma unroll 2
  for (int dd = 0; dd < D / 2; dd += 4) {
    int d = dbase + dd;
    float w0 = W[(d + 0) * A + a];
    float w1 = W[(d + 1) * A + a];
    float w2 = W[(d + 2) * A + a];
    float w3 = W[(d + 3) * A + a];
#pragma unroll
    for (int j = 0; j < 8; ++j) {
      float4 x = *(const float4*)&xs[j][d];   // wave-uniform addr -> broadcast
      acc[j] = fmaf(x.x, w0, acc[j]);
      acc[j] = fmaf(x.y, w1, acc[j]);
      acc[j] = fmaf(x.z, w2, acc[j]);
      acc[j] = fmaf(x.w, w3, acc[j]);
    }
  }
#pragma unroll
  for (int j = 0; j < 8; ++j) ps[j][h][a] = acc[j];
  __syncthreads();

  float bz = bias[a];
  if (isQ) {
#pragma unroll
    for (int j = h * 4; j < h * 4 + 4; ++j) {
      float t = ps[j][0][a] + ps[j][1][a] + bz;
      Eq[(size_t)(r0 + j) * A + a] = __builtin_amdgcn_exp2f(t * TWO_LOG2E);
    }
  } else {
#pragma unroll
    for (int j = h * 4; j < h * 4 + 4; ++j) {
      float t = ps[j][0][a] + ps[j][1][a] + bz;
      es[a][j] = __builtin_amdgcn_exp2f(t * TWO_LOG2E);
    }
    __syncthreads();
    int b  = r0 >> 10;          // TV == 1024
    int v0 = r0 & (TV - 1);
    for (int i = threadIdx.x; i < A * 8; i += 256) {
      int aa = i >> 3, jj = i & 7;
      EkT[((size_t)b * A + aa) * TV + v0 + jj] = es[aa][jj];
    }
  }
}

// ---------------------------------------------------------------------------
// Scores + softmax for one (b,q) row.
//   score[v] = sumV - 2 * sum_a v_a / (Eq[a]*EkT[a,v] + 1)
// Block = 512 threads (8 waves), each thread owns 2 v's. EkT reads are
// lane-coalesced (consecutive v). Eq/attn_v reads are wave-uniform -> scalar.
// 4 independent accumulator chains for ILP.
// ---------------------------------------------------------------------------
__global__ __launch_bounds__(512, 8) void score_softmax_kernel(
    const float* __restrict__ Eq, const float* __restrict__ EkT,
    const float* __restrict__ attn_v, const int* __restrict__ mask,
    float* __restrict__ attn) {
  __shared__ float red[8];
  __shared__ float bc[2];

  int bq  = blockIdx.x;      // b*TQ + q
  int b   = bq >> 8;         // TQ == 256
  int tid = threadIdx.x;

  const float* eqrow = Eq + (size_t)bq * A;

  float sumV = 0.f;
#pragma unroll 16
  for (int i = 0; i < A; ++i) sumV += attn_v[i];

  float scv[2];
  float lmax = -INFINITY;
#pragma unroll
  for (int u = 0; u < 2; ++u) {
    int v = tid + u * 512;
    const float* ek = EkT + (size_t)b * A * TV + v;
    float s0 = 0.f, s1 = 0.f, s2 = 0.f, s3 = 0.f;
#pragma unroll 4
    for (int i = 0; i < A; i += 4) {
      float e0 = ek[(i + 0) * TV];
      float e1 = ek[(i + 1) * TV];
      float e2 = ek[(i + 2) * TV];
      float e3 = ek[(i + 3) * TV];
      s0 += attn_v[i + 0] * __builtin_amdgcn_rcpf(fmaf(e0, eqrow[i + 0], 1.f));
      s1 += attn_v[i + 1] * __builtin_amdgcn_rcpf(fmaf(e1, eqrow[i + 1], 1.f));
      s2 += attn_v[i + 2] * __builtin_amdgcn_rcpf(fmaf(e2, eqrow[i + 2], 1.f));
      s3 += attn_v[i + 3] * __builtin_amdgcn_rcpf(fmaf(e3, eqrow[i + 3], 1.f));
    }
    float s = sumV - 2.f * ((s0 + s1) + (s2 + s3));
    s += (1.f - (float)mask[b * TV + v]) * NEG_BIG_F;
    scv[u] = s;
    lmax = fmaxf(lmax, s);
  }

  // block max (8 waves)
  for (int off = 32; off > 0; off >>= 1)
    lmax = fmaxf(lmax, __shfl_down(lmax, off, 64));
  if ((tid & 63) == 0) red[tid >> 6] = lmax;
  __syncthreads();
  if (tid == 0) {
    float m = red[0];
#pragma unroll
    for (int i = 1; i < 8; ++i) m = fmaxf(m, red[i]);
    bc[0] = m;
  }
  __syncthreads();
  float m = bc[0];

  float e0 = __builtin_amdgcn_exp2f((scv[0] - m) * LOG2E);
  float e1 = __builtin_amdgcn_exp2f((scv[1] - m) * LOG2E);
  float lsum = e0 + e1;
  for (int off = 32; off > 0; off >>= 1)
    lsum += __shfl_down(lsum, off, 64);
  __syncthreads();   // protect red[] before rewrite
  if ((tid & 63) == 0) red[tid >> 6] = lsum;
  __syncthreads();
  if (tid == 0) {
    float s = 0.f;
#pragma unroll
    for (int i = 0; i < 8; ++i) s += red[i];
    bc[1] = s;
  }
  __syncthreads();
  float inv = 1.f / bc[1];

  float* arow = attn + (size_t)bq * TV;
  arow[tid]       = e0 * inv;
  arow[tid + 512] = e1 * inv;
}

// ---------------------------------------------------------------------------
// out[b,q,:] = sum_v attn[b,q,v] * inputs[b,v,:]
// Block = 512 threads (8 waves): 64 float2 d-columns x 8 q-groups x 2 q.
// Tile 16 q x 128 d; attn chunk in LDS (broadcast); X float2 coalesced,
// redundant across q-groups (L1 broadcast). grid 256 blocks x 8 waves = 100%.
// ---------------------------------------------------------------------------
__global__ __launch_bounds__(512, 8) void pv_kernel(
    const float* __restrict__ attn, const float* __restrict__ X,
    float* __restrict__ out) {
  const int QT = 16, VC = 128;
  __shared__ float at[QT][VC];    // 8 KB
  int b = blockIdx.z, qt = blockIdx.y, dt = blockIdx.x;
  int tid  = threadIdx.x;
  int dcol = tid & 63;            // 64 float2 columns = 128 d
  int qg   = tid >> 6;            // 0..7, 2 q's each
  int d0 = dt * 128 + dcol * 2;
  int q0 = qt * QT;

  float2 acc0 = make_float2(0.f, 0.f), acc1 = make_float2(0.f, 0.f);

  for (int vc = 0; vc < TV; vc += VC) {
    for (int i = tid; i < QT * VC; i += 512) {
      at[i >> 7][i & (VC - 1)] =
          attn[(size_t)(b * TQ + q0 + (i >> 7)) * TV + vc + (i & (VC - 1))];
    }
    __syncthreads();
#pragma unroll 4
    for (int vi = 0; vi < VC; ++vi) {
      float2 x = *(const float2*)(X + (size_t)(b * TV + vc + vi) * D + d0);
      float w0 = at[qg * 2 + 0][vi];
      float w1 = at[qg * 2 + 1][vi];
      acc0.x = fmaf(w0, x.x, acc0.x);
      acc0.y = fmaf(w0, x.y, acc0.y);
      acc1.x = fmaf(w1, x.x, acc1.x);
      acc1.y = fmaf(w1, x.y, acc1.y);
    }
    __syncthreads();
  }
  int q = q0 + qg * 2;
  *(float2*)(out + (size_t)(b * TQ + q) * D + d0)     = acc0;
  *(float2*)(out + (size_t)(b * TQ + q + 1) * D + d0) = acc1;
}

extern "C" void kernel_launch(void* const* d_in, const int* in_sizes, int n_in,
                              void* d_out, int out_size, void* d_ws, size_t ws_size,
                              hipStream_t stream) {
  const float* inputs  = (const float*)d_in[0];  // [B,TV,D]
  const float* context = (const float*)d_in[1];  // [B,TQ,D]
  const int*   mask    = (const int*)d_in[2];    // [B,TV]
  const float* Wk      = (const float*)d_in[3];  // [D,A]
  const float* bk      = (const float*)d_in[4];  // [A]
  const float* Wq      = (const float*)d_in[5];  // [D,A]
  const float* bq      = (const float*)d_in[6];  // [A]
  const float* attn_v  = (const float*)d_in[7];  // [A]
  float* out = (float*)d_out;                    // [B,TQ,D]

  // Workspace layout (fp32): Eq | EkT | attn  = 0.5MB + 2MB + 4MB
  float* Eq   = (float*)d_ws;           // [B*TQ, A]
  float* EkT  = Eq + B * TQ * A;        // [B, A, TV]  (transposed!)
  float* attn = EkT + (size_t)B * A * TV; // [B*TQ, TV]

  proj_exp_kernel<<<QBLK + KBLK, 256, 0, stream>>>(context, inputs, Wq, bq,
                                                   Wk, bk, Eq, EkT);
  score_softmax_kernel<<<B * TQ, 512, 0, stream>>>(Eq, EkT, attn_v, mask, attn);
  pv_kernel<<<dim3(4, 16, 4), 512, 0, stream>>>(attn, inputs, out);
}

// Round 3
// 187.210 us; speedup vs baseline: 1.6554x; 1.1052x over previous
//
#include <hip/hip_runtime.h>
#include <math.h>

// Problem sizes (fixed by the reference)
#define B   4
#define TQ  256
#define TV  1024
#define D   512
#define A   128

#define LOG2E     1.4426950408889634f
#define TWO_LOG2E 2.8853900817779268f
#define NEG_BIG_F (-1e9f)

#define QBLK (B * TQ / 8)   // 128 q-projection blocks
#define KBLK (B * TV / 8)   // 512 k-projection blocks

// ---------------------------------------------------------------------------
// Fused projection + exp(2x) for BOTH q and k.
//   q path: Eq[r, a]     = exp(2*(ctx[r,:]@Wq[:,a] + bq[a]))   [row-major]
//   k path: EkT[b, a, v] = exp(2*(inp[r,:]@Wk[:,a] + bk[a]))   [TRANSPOSED]
// Block: 512 threads = (a 0..127, quarter h 0..3 splitting d). 8 rows/block.
// 8 waves/block for latency hiding; partial sums reduced through LDS.
// ---------------------------------------------------------------------------
__global__ __launch_bounds__(512) void proj_exp_kernel(
    const float* __restrict__ ctx, const float* __restrict__ inp,
    const float* __restrict__ Wq, const float* __restrict__ bq,
    const float* __restrict__ Wk, const float* __restrict__ bk,
    float* __restrict__ Eq, float* __restrict__ EkT) {
  __shared__ float xs[8][D];        // 16 KB
  __shared__ float ps[8][4][A];     // 16 KB (row j, quarter, a)
  __shared__ float es[A][9];        // 4.6 KB (transpose staging, +1 pad)

  bool isQ = blockIdx.x < QBLK;
  const float* X; const float* W; const float* bias; int r0;
  if (isQ) { X = ctx; W = Wq; bias = bq; r0 = blockIdx.x * 8; }
  else     { X = inp; W = Wk; bias = bk; r0 = (blockIdx.x - QBLK) * 8; }

  // stage 8 rows of X (float4, coalesced)
  {
    const float4* Xv = (const float4*)(X + (size_t)r0 * D);
    float4* xsv = (float4*)&xs[0][0];
    for (int i = threadIdx.x; i < 8 * D / 4; i += 512) xsv[i] = Xv[i];
  }
  __syncthreads();

  int a = threadIdx.x & 127;
  int h = threadIdx.x >> 7;        // 0..3, splits d-range into quarters
  float acc[8];
#pragma unroll
  for (int j = 0; j < 8; ++j) acc[j] = 0.f;

  int dbase = h * (D / 4);
#pragma unroll 2
  for (int dd = 0; dd < D / 4; dd += 4) {
    int d = dbase + dd;
    float w0 = W[(d + 0) * A + a];
    float w1 = W[(d + 1) * A + a];
    float w2 = W[(d + 2) * A + a];
    float w3 = W[(d + 3) * A + a];
#pragma unroll
    for (int j = 0; j < 8; ++j) {
      float4 x = *(const float4*)&xs[j][d];   // wave-uniform addr -> broadcast
      acc[j] = fmaf(x.x, w0, acc[j]);
      acc[j] = fmaf(x.y, w1, acc[j]);
      acc[j] = fmaf(x.z, w2, acc[j]);
      acc[j] = fmaf(x.w, w3, acc[j]);
    }
  }
#pragma unroll
  for (int j = 0; j < 8; ++j) ps[j][h][a] = acc[j];
  __syncthreads();

  float bz = bias[a];
  if (isQ) {
#pragma unroll
    for (int j = h * 2; j < h * 2 + 2; ++j) {
      float t = ((ps[j][0][a] + ps[j][1][a]) + (ps[j][2][a] + ps[j][3][a])) + bz;
      Eq[(size_t)(r0 + j) * A + a] = __builtin_amdgcn_exp2f(t * TWO_LOG2E);
    }
  } else {
#pragma unroll
    for (int j = h * 2; j < h * 2 + 2; ++j) {
      float t = ((ps[j][0][a] + ps[j][1][a]) + (ps[j][2][a] + ps[j][3][a])) + bz;
      es[a][j] = __builtin_amdgcn_exp2f(t * TWO_LOG2E);
    }
    __syncthreads();
    int b  = r0 >> 10;          // TV == 1024
    int v0 = r0 & (TV - 1);
    for (int i = threadIdx.x; i < A * 8; i += 512) {
      int aa = i >> 3, jj = i & 7;
      EkT[((size_t)b * A + aa) * TV + v0 + jj] = es[aa][jj];
    }
  }
}

// ---------------------------------------------------------------------------
// Scores + softmax for TWO (b,q) rows per block (shares EkT loads).
//   score[v] = sumV - 2 * sum_a v_a / (Eq[a]*EkT[a,v] + 1)
// Block = 512 threads (8 waves), each thread owns 2 v's x 2 q's.
// EkT reads lane-coalesced; Eq/attn_v wave-uniform -> scalar regs.
// Also zero-fills d_out (consumed later by pv's atomics).
// ---------------------------------------------------------------------------
__global__ __launch_bounds__(512, 8) void score_softmax_kernel(
    const float* __restrict__ Eq, const float* __restrict__ EkT,
    const float* __restrict__ attn_v, const int* __restrict__ mask,
    float* __restrict__ attn, float* __restrict__ outz) {
  __shared__ float red0[8], red1[8];
  __shared__ float bc[4];

  int tid = threadIdx.x;
  // zero d_out: 512 blocks x 512 threads x float2 == B*TQ*D floats
  ((float2*)outz)[(size_t)blockIdx.x * 512 + tid] = make_float2(0.f, 0.f);

  int bq0 = blockIdx.x * 2;  // first of two q rows
  int b   = bq0 >> 8;        // TQ == 256

  const float* eq0 = Eq + (size_t)bq0 * A;
  const float* eq1 = eq0 + A;

  float sumV = 0.f;
#pragma unroll 16
  for (int i = 0; i < A; ++i) sumV += attn_v[i];

  float scv[2][2];           // [u][q]
  float lmax0 = -INFINITY, lmax1 = -INFINITY;
#pragma unroll
  for (int u = 0; u < 2; ++u) {
    int v = tid + u * 512;
    const float* ek = EkT + (size_t)b * A * TV + v;
    float a00 = 0.f, a01 = 0.f, a10 = 0.f, a11 = 0.f;  // [q][chain]
#pragma unroll 4
    for (int i = 0; i < A; i += 2) {
      float e0  = ek[(i + 0) * TV];
      float e1  = ek[(i + 1) * TV];
      float av0 = attn_v[i + 0];
      float av1 = attn_v[i + 1];
      a00 += av0 * __builtin_amdgcn_rcpf(fmaf(e0, eq0[i + 0], 1.f));
      a01 += av1 * __builtin_amdgcn_rcpf(fmaf(e1, eq0[i + 1], 1.f));
      a10 += av0 * __builtin_amdgcn_rcpf(fmaf(e0, eq1[i + 0], 1.f));
      a11 += av1 * __builtin_amdgcn_rcpf(fmaf(e1, eq1[i + 1], 1.f));
    }
    float msk = (1.f - (float)mask[b * TV + v]) * NEG_BIG_F;
    float s0 = sumV - 2.f * (a00 + a01) + msk;
    float s1 = sumV - 2.f * (a10 + a11) + msk;
    scv[u][0] = s0; scv[u][1] = s1;
    lmax0 = fmaxf(lmax0, s0);
    lmax1 = fmaxf(lmax1, s1);
  }

  // block max (8 waves), both q rows at once
  for (int off = 32; off > 0; off >>= 1) {
    lmax0 = fmaxf(lmax0, __shfl_down(lmax0, off, 64));
    lmax1 = fmaxf(lmax1, __shfl_down(lmax1, off, 64));
  }
  if ((tid & 63) == 0) { red0[tid >> 6] = lmax0; red1[tid >> 6] = lmax1; }
  __syncthreads();
  if (tid == 0) {
    float m0 = red0[0], m1 = red1[0];
#pragma unroll
    for (int i = 1; i < 8; ++i) { m0 = fmaxf(m0, red0[i]); m1 = fmaxf(m1, red1[i]); }
    bc[0] = m0; bc[1] = m1;
  }
  __syncthreads();
  float m0 = bc[0], m1 = bc[1];

  float e00 = __builtin_amdgcn_exp2f((scv[0][0] - m0) * LOG2E);
  float e10 = __builtin_amdgcn_exp2f((scv[1][0] - m0) * LOG2E);
  float e01 = __builtin_amdgcn_exp2f((scv[0][1] - m1) * LOG2E);
  float e11 = __builtin_amdgcn_exp2f((scv[1][1] - m1) * LOG2E);
  float ls0 = e00 + e10, ls1 = e01 + e11;
  for (int off = 32; off > 0; off >>= 1) {
    ls0 += __shfl_down(ls0, off, 64);
    ls1 += __shfl_down(ls1, off, 64);
  }
  __syncthreads();   // protect red[] before rewrite
  if ((tid & 63) == 0) { red0[tid >> 6] = ls0; red1[tid >> 6] = ls1; }
  __syncthreads();
  if (tid == 0) {
    float s0 = 0.f, s1 = 0.f;
#pragma unroll
    for (int i = 0; i < 8; ++i) { s0 += red0[i]; s1 += red1[i]; }
    bc[2] = s0; bc[3] = s1;
  }
  __syncthreads();
  float inv0 = 1.f / bc[2];
  float inv1 = 1.f / bc[3];

  float* arow0 = attn + (size_t)bq0 * TV;
  float* arow1 = arow0 + TV;
  arow0[tid]       = e00 * inv0;
  arow0[tid + 512] = e10 * inv0;
  arow1[tid]       = e01 * inv1;
  arow1[tid + 512] = e11 * inv1;
}

// ---------------------------------------------------------------------------
// out[b,q,:] += sum_{v in split} attn[b,q,v] * inputs[b,v,:]
// grid (dt*vs=16, qt=16, b=4) = 1024 blocks x 512 threads (8 waves) -> 100%
// occupancy ceiling, 4 blocks/CU. Each block: 128-d slice, 256-v range,
// 16 q. float4 X loads; partials combined with native fp32 atomics
// (out pre-zeroed by score kernel).
// ---------------------------------------------------------------------------
__global__ __launch_bounds__(512, 8) void pv_kernel(
    const float* __restrict__ attn, const float* __restrict__ X,
    float* __restrict__ out) {
  const int QT = 16, VC = 128;
  __shared__ float at[QT][VC];    // 8 KB
  int b  = blockIdx.z;
  int qt = blockIdx.y;
  int dt = blockIdx.x & 3;        // 4 d-slices of 128
  int vs = blockIdx.x >> 2;       // 4 v-splits of 256
  int tid  = threadIdx.x;
  int dcol = tid & 31;            // 32 float4 columns = 128 d
  int qg   = tid >> 5;            // 0..15, one q each
  int d0 = dt * 128 + dcol * 4;
  int q0 = qt * QT;

  float4 acc = make_float4(0.f, 0.f, 0.f, 0.f);

  for (int vc = vs * 256; vc < vs * 256 + 256; vc += VC) {
    for (int i = tid; i < QT * VC; i += 512) {
      at[i >> 7][i & (VC - 1)] =
          attn[(size_t)(b * TQ + q0 + (i >> 7)) * TV + vc + (i & (VC - 1))];
    }
    __syncthreads();
#pragma unroll 4
    for (int vi = 0; vi < VC; ++vi) {
      float4 x = *(const float4*)(X + (size_t)(b * TV + vc + vi) * D + d0);
      float w = at[qg][vi];
      acc.x = fmaf(w, x.x, acc.x);
      acc.y = fmaf(w, x.y, acc.y);
      acc.z = fmaf(w, x.z, acc.z);
      acc.w = fmaf(w, x.w, acc.w);
    }
    __syncthreads();
  }
  float* o = out + (size_t)(b * TQ + q0 + qg) * D + d0;
  unsafeAtomicAdd(o + 0, acc.x);
  unsafeAtomicAdd(o + 1, acc.y);
  unsafeAtomicAdd(o + 2, acc.z);
  unsafeAtomicAdd(o + 3, acc.w);
}

extern "C" void kernel_launch(void* const* d_in, const int* in_sizes, int n_in,
                              void* d_out, int out_size, void* d_ws, size_t ws_size,
                              hipStream_t stream) {
  const float* inputs  = (const float*)d_in[0];  // [B,TV,D]
  const float* context = (const float*)d_in[1];  // [B,TQ,D]
  const int*   mask    = (const int*)d_in[2];    // [B,TV]
  const float* Wk      = (const float*)d_in[3];  // [D,A]
  const float* bk      = (const float*)d_in[4];  // [A]
  const float* Wq      = (const float*)d_in[5];  // [D,A]
  const float* bq      = (const float*)d_in[6];  // [A]
  const float* attn_v  = (const float*)d_in[7];  // [A]
  float* out = (float*)d_out;                    // [B,TQ,D]

  // Workspace layout (fp32): Eq | EkT | attn  = 0.5MB + 2MB + 4MB
  float* Eq   = (float*)d_ws;             // [B*TQ, A]
  float* EkT  = Eq + B * TQ * A;          // [B, A, TV]  (transposed!)
  float* attn = EkT + (size_t)B * A * TV; // [B*TQ, TV]

  proj_exp_kernel<<<QBLK + KBLK, 512, 0, stream>>>(context, inputs, Wq, bq,
                                                   Wk, bk, Eq, EkT);
  score_softmax_kernel<<<B * TQ / 2, 512, 0, stream>>>(Eq, EkT, attn_v, mask,
                                                       attn, out);
  pv_kernel<<<dim3(16, 16, 4), 512, 0, stream>>>(attn, inputs, out);
}

// Round 4
// 170.233 us; speedup vs baseline: 1.8204x; 1.0997x over previous
//
#include <hip/hip_runtime.h>
#include <math.h>

// Problem sizes (fixed by the reference)
#define B   4
#define TQ  256
#define TV  1024
#define D   512
#define A   128

#define LOG2E     1.4426950408889634f
#define TWO_LOG2E 2.8853900817779268f
#define NEG_BIG_F (-1e9f)

#define QBLK (B * TQ / 8)   // 128 q-projection blocks
#define KBLK (B * TV / 8)   // 512 k-projection blocks

// ---------------------------------------------------------------------------
// Fused projection + exp(2x) for BOTH q and k. Also zero-fills d_out for the
// pv kernel's atomics (stream-ordered, runs first).
//   q path: Eq[r, a]     = exp(2*(ctx[r,:]@Wq[:,a] + bq[a]))   [row-major]
//   k path: EkT[b, a, v] = exp(2*(inp[r,:]@Wk[:,a] + bk[a]))   [TRANSPOSED]
// ---------------------------------------------------------------------------
__global__ __launch_bounds__(512) void proj_exp_kernel(
    const float* __restrict__ ctx, const float* __restrict__ inp,
    const float* __restrict__ Wq, const float* __restrict__ bq,
    const float* __restrict__ Wk, const float* __restrict__ bk,
    float* __restrict__ Eq, float* __restrict__ EkT,
    float* __restrict__ outz) {
  __shared__ float xs[8][D];        // 16 KB
  __shared__ float ps[8][4][A];     // 16 KB (row j, quarter, a)
  __shared__ float es[A][9];        // 4.6 KB (transpose staging, +1 pad)

  // zero d_out: B*TQ*D floats = 131072 float4; grid has 640*512 threads
  {
    size_t gid = (size_t)blockIdx.x * 512 + threadIdx.x;
    if (gid < (size_t)(B * TQ * D / 4))
      ((float4*)outz)[gid] = make_float4(0.f, 0.f, 0.f, 0.f);
  }

  bool isQ = blockIdx.x < QBLK;
  const float* X; const float* W; const float* bias; int r0;
  if (isQ) { X = ctx; W = Wq; bias = bq; r0 = blockIdx.x * 8; }
  else     { X = inp; W = Wk; bias = bk; r0 = (blockIdx.x - QBLK) * 8; }

  // stage 8 rows of X (float4, coalesced)
  {
    const float4* Xv = (const float4*)(X + (size_t)r0 * D);
    float4* xsv = (float4*)&xs[0][0];
    for (int i = threadIdx.x; i < 8 * D / 4; i += 512) xsv[i] = Xv[i];
  }
  __syncthreads();

  int a = threadIdx.x & 127;
  int h = threadIdx.x >> 7;        // 0..3, splits d-range into quarters
  float acc[8];
#pragma unroll
  for (int j = 0; j < 8; ++j) acc[j] = 0.f;

  int dbase = h * (D / 4);
#pragma unroll 2
  for (int dd = 0; dd < D / 4; dd += 4) {
    int d = dbase + dd;
    float w0 = W[(d + 0) * A + a];
    float w1 = W[(d + 1) * A + a];
    float w2 = W[(d + 2) * A + a];
    float w3 = W[(d + 3) * A + a];
#pragma unroll
    for (int j = 0; j < 8; ++j) {
      float4 x = *(const float4*)&xs[j][d];   // wave-uniform addr -> broadcast
      acc[j] = fmaf(x.x, w0, acc[j]);
      acc[j] = fmaf(x.y, w1, acc[j]);
      acc[j] = fmaf(x.z, w2, acc[j]);
      acc[j] = fmaf(x.w, w3, acc[j]);
    }
  }
#pragma unroll
  for (int j = 0; j < 8; ++j) ps[j][h][a] = acc[j];
  __syncthreads();

  float bz = bias[a];
  if (isQ) {
#pragma unroll
    for (int j = h * 2; j < h * 2 + 2; ++j) {
      float t = ((ps[j][0][a] + ps[j][1][a]) + (ps[j][2][a] + ps[j][3][a])) + bz;
      Eq[(size_t)(r0 + j) * A + a] = __builtin_amdgcn_exp2f(t * TWO_LOG2E);
    }
  } else {
#pragma unroll
    for (int j = h * 2; j < h * 2 + 2; ++j) {
      float t = ((ps[j][0][a] + ps[j][1][a]) + (ps[j][2][a] + ps[j][3][a])) + bz;
      es[a][j] = __builtin_amdgcn_exp2f(t * TWO_LOG2E);
    }
    __syncthreads();
    int b  = r0 >> 10;          // TV == 1024
    int v0 = r0 & (TV - 1);
    for (int i = threadIdx.x; i < A * 8; i += 512) {
      int aa = i >> 3, jj = i & 7;
      EkT[((size_t)b * A + aa) * TV + v0 + jj] = es[aa][jj];
    }
  }
}

// ---------------------------------------------------------------------------
// Scores + softmax, TWO (b,q) rows per block, 1024 threads (16 waves).
// Each thread owns ONE v (v = tid); EkT loads (lane-coalesced) shared by the
// two q rows. 512 blocks x 16 waves -> 32 waves/CU ceiling (100%).
//   score[v] = sumV - 2 * sum_a v_a / (Eq[a]*EkT[a,v] + 1)
// ---------------------------------------------------------------------------
__global__ __launch_bounds__(1024, 8) void score_softmax_kernel(
    const float* __restrict__ Eq, const float* __restrict__ EkT,
    const float* __restrict__ attn_v, const int* __restrict__ mask,
    float* __restrict__ attn) {
  __shared__ float red0[16], red1[16];
  __shared__ float bc[4];

  int tid = threadIdx.x;
  int bq0 = blockIdx.x * 2;  // first of two q rows
  int b   = bq0 >> 8;        // TQ == 256

  const float* eq0 = Eq + (size_t)bq0 * A;
  const float* eq1 = eq0 + A;

  float sumV = 0.f;
#pragma unroll 16
  for (int i = 0; i < A; ++i) sumV += attn_v[i];

  int v = tid;
  const float* ek = EkT + (size_t)b * A * TV + v;
  float a00 = 0.f, a01 = 0.f, a10 = 0.f, a11 = 0.f;  // [q][chain]
#pragma unroll 8
  for (int i = 0; i < A; i += 2) {
    float e0  = ek[(i + 0) * TV];
    float e1  = ek[(i + 1) * TV];
    float av0 = attn_v[i + 0];
    float av1 = attn_v[i + 1];
    a00 += av0 * __builtin_amdgcn_rcpf(fmaf(e0, eq0[i + 0], 1.f));
    a01 += av1 * __builtin_amdgcn_rcpf(fmaf(e1, eq0[i + 1], 1.f));
    a10 += av0 * __builtin_amdgcn_rcpf(fmaf(e0, eq1[i + 0], 1.f));
    a11 += av1 * __builtin_amdgcn_rcpf(fmaf(e1, eq1[i + 1], 1.f));
  }
  float msk = (1.f - (float)mask[b * TV + v]) * NEG_BIG_F;
  float s0 = sumV - 2.f * (a00 + a01) + msk;
  float s1 = sumV - 2.f * (a10 + a11) + msk;

  // block max (16 waves), both q rows at once
  float lmax0 = s0, lmax1 = s1;
  for (int off = 32; off > 0; off >>= 1) {
    lmax0 = fmaxf(lmax0, __shfl_down(lmax0, off, 64));
    lmax1 = fmaxf(lmax1, __shfl_down(lmax1, off, 64));
  }
  if ((tid & 63) == 0) { red0[tid >> 6] = lmax0; red1[tid >> 6] = lmax1; }
  __syncthreads();
  if (tid == 0) {
    float m0 = red0[0], m1 = red1[0];
#pragma unroll
    for (int i = 1; i < 16; ++i) { m0 = fmaxf(m0, red0[i]); m1 = fmaxf(m1, red1[i]); }
    bc[0] = m0; bc[1] = m1;
  }
  __syncthreads();
  float m0 = bc[0], m1 = bc[1];

  float e0 = __builtin_amdgcn_exp2f((s0 - m0) * LOG2E);
  float e1 = __builtin_amdgcn_exp2f((s1 - m1) * LOG2E);
  float ls0 = e0, ls1 = e1;
  for (int off = 32; off > 0; off >>= 1) {
    ls0 += __shfl_down(ls0, off, 64);
    ls1 += __shfl_down(ls1, off, 64);
  }
  __syncthreads();   // protect red[] before rewrite
  if ((tid & 63) == 0) { red0[tid >> 6] = ls0; red1[tid >> 6] = ls1; }
  __syncthreads();
  if (tid == 0) {
    float t0 = 0.f, t1 = 0.f;
#pragma unroll
    for (int i = 0; i < 16; ++i) { t0 += red0[i]; t1 += red1[i]; }
    bc[2] = t0; bc[3] = t1;
  }
  __syncthreads();

  attn[(size_t)bq0 * TV + v]       = e0 * (1.f / bc[2]);
  attn[(size_t)(bq0 + 1) * TV + v] = e1 * (1.f / bc[3]);
}

// ---------------------------------------------------------------------------
// out[b,q,:] += sum_{v-range} attn[b,q,v] * inputs[b,v,:]
// Register-blocked: each thread computes 4q x 4d (16 acc), 4 vi per unit ->
// 64 FMA per (4 global float4 + 4 LDS float4-broadcast). Tile 64q x 128d x
// 256v per block, v staged in 2 chunks of 128; attn tile in LDS.
// grid (dt4*vs4, qt4, b4) = 256 blocks x 512 thr. Atomic-add partials
// (out pre-zeroed by proj kernel).
// ---------------------------------------------------------------------------
__global__ __launch_bounds__(512, 4) void pv_kernel(
    const float* __restrict__ attn, const float* __restrict__ X,
    float* __restrict__ out) {
  __shared__ float at[64][128];   // 32 KB attn tile (q, v-chunk)
  int b  = blockIdx.z;
  int qt = blockIdx.y;
  int dt = blockIdx.x & 3;        // 4 d-slices of 128
  int vs = blockIdx.x >> 2;       // 4 v-splits of 256
  int tid  = threadIdx.x;
  int dcol = tid & 31;            // 32 float4 columns = 128 d
  int qg   = tid >> 5;            // 0..15 q-groups of 4
  int d0 = dt * 128 + dcol * 4;
  int q0 = qt * 64;
  int qq = qg * 4;

  float4 acc[4];
#pragma unroll
  for (int j = 0; j < 4; ++j) acc[j] = make_float4(0.f, 0.f, 0.f, 0.f);

  for (int c = 0; c < 2; ++c) {
    int vbase = vs * 256 + c * 128;
    // stage attn tile: 64 q x 128 v = 2048 float4 loads
    for (int i = tid; i < 64 * 32; i += 512) {
      int row = i >> 5, c4 = i & 31;
      ((float4*)&at[row][0])[c4] =
          *(const float4*)(attn + (size_t)(b * TQ + q0 + row) * TV + vbase + c4 * 4);
    }
    __syncthreads();

    const float* Xb = X + ((size_t)b * TV + vbase) * D + d0;
    for (int vi = 0; vi < 128; vi += 4) {
      float4 x0 = *(const float4*)(Xb + (size_t)(vi + 0) * D);
      float4 x1 = *(const float4*)(Xb + (size_t)(vi + 1) * D);
      float4 x2 = *(const float4*)(Xb + (size_t)(vi + 2) * D);
      float4 x3 = *(const float4*)(Xb + (size_t)(vi + 3) * D);
#pragma unroll
      for (int j = 0; j < 4; ++j) {
        float4 av = *(const float4*)&at[qq + j][vi];  // 2-addr broadcast
        acc[j].x = fmaf(av.x, x0.x, acc[j].x);
        acc[j].y = fmaf(av.x, x0.y, acc[j].y);
        acc[j].z = fmaf(av.x, x0.z, acc[j].z);
        acc[j].w = fmaf(av.x, x0.w, acc[j].w);
        acc[j].x = fmaf(av.y, x1.x, acc[j].x);
        acc[j].y = fmaf(av.y, x1.y, acc[j].y);
        acc[j].z = fmaf(av.y, x1.z, acc[j].z);
        acc[j].w = fmaf(av.y, x1.w, acc[j].w);
        acc[j].x = fmaf(av.z, x2.x, acc[j].x);
        acc[j].y = fmaf(av.z, x2.y, acc[j].y);
        acc[j].z = fmaf(av.z, x2.z, acc[j].z);
        acc[j].w = fmaf(av.z, x2.w, acc[j].w);
        acc[j].x = fmaf(av.w, x3.x, acc[j].x);
        acc[j].y = fmaf(av.w, x3.y, acc[j].y);
        acc[j].z = fmaf(av.w, x3.z, acc[j].z);
        acc[j].w = fmaf(av.w, x3.w, acc[j].w);
      }
    }
    __syncthreads();
  }

#pragma unroll
  for (int j = 0; j < 4; ++j) {
    float* o = out + (size_t)(b * TQ + q0 + qq + j) * D + d0;
    unsafeAtomicAdd(o + 0, acc[j].x);
    unsafeAtomicAdd(o + 1, acc[j].y);
    unsafeAtomicAdd(o + 2, acc[j].z);
    unsafeAtomicAdd(o + 3, acc[j].w);
  }
}

extern "C" void kernel_launch(void* const* d_in, const int* in_sizes, int n_in,
                              void* d_out, int out_size, void* d_ws, size_t ws_size,
                              hipStream_t stream) {
  const float* inputs  = (const float*)d_in[0];  // [B,TV,D]
  const float* context = (const float*)d_in[1];  // [B,TQ,D]
  const int*   mask    = (const int*)d_in[2];    // [B,TV]
  const float* Wk      = (const float*)d_in[3];  // [D,A]
  const float* bk      = (const float*)d_in[4];  // [A]
  const float* Wq      = (const float*)d_in[5];  // [D,A]
  const float* bq      = (const float*)d_in[6];  // [A]
  const float* attn_v  = (const float*)d_in[7];  // [A]
  float* out = (float*)d_out;                    // [B,TQ,D]

  // Workspace layout (fp32): Eq | EkT | attn  = 0.5MB + 2MB + 4MB
  float* Eq   = (float*)d_ws;             // [B*TQ, A]
  float* EkT  = Eq + B * TQ * A;          // [B, A, TV]  (transposed!)
  float* attn = EkT + (size_t)B * A * TV; // [B*TQ, TV]

  proj_exp_kernel<<<QBLK + KBLK, 512, 0, stream>>>(context, inputs, Wq, bq,
                                                   Wk, bk, Eq, EkT, out);
  score_softmax_kernel<<<B * TQ / 2, 1024, 0, stream>>>(Eq, EkT, attn_v, mask,
                                                        attn);
  pv_kernel<<<dim3(16, 4, 4), 512, 0, stream>>>(attn, inputs, out);
}